// Round 1
// baseline (48245.438 us; speedup 1.0000x reference)
//
#include <hip/hip_runtime.h>
#include <cmath>

// Problem constants
#define LSEQ 512
#define NBAT 32
#define HDIM 512
#define PADH 34   // h_lds row pad (floats)

__device__ __forceinline__ float sigf(float x) { return 1.f / (1.f + __expf(-x)); }

// ---------------------------------------------------------------------------
// GEMM: C[M,N] = A[M,K] @ B[N,K]^T + bias1 (+ bias2)
// gmode=1: scatter-store into G layout [t][g][b][j]  (row m = b*512+t, col n = g*512+j)
// ---------------------------------------------------------------------------
__global__ __launch_bounds__(256) void gemm64(
    const float* __restrict__ A, const float* __restrict__ B,
    const float* __restrict__ bias1, const float* __restrict__ bias2,
    float* __restrict__ C, int M, int N, int K, int gmode) {
  __shared__ float As[16][64];
  __shared__ float Bs[16][64];
  const int n0 = blockIdx.x * 64, m0 = blockIdx.y * 64;
  const int t = threadIdx.x;
  const int li = t & 63, lq = t >> 6;
  const int tx = t & 15, ty = t >> 4;
  float acc[4][4] = {};
  const float* Ap = A + (size_t)(m0 + li) * K + lq * 4;
  const float* Bp = B + (size_t)(n0 + li) * K + lq * 4;
  for (int k0 = 0; k0 < K; k0 += 16) {
    float4 av = *(const float4*)(Ap + k0);
    float4 bv = *(const float4*)(Bp + k0);
    __syncthreads();
    As[lq*4+0][li] = av.x; As[lq*4+1][li] = av.y;
    As[lq*4+2][li] = av.z; As[lq*4+3][li] = av.w;
    Bs[lq*4+0][li] = bv.x; Bs[lq*4+1][li] = bv.y;
    Bs[lq*4+2][li] = bv.z; Bs[lq*4+3][li] = bv.w;
    __syncthreads();
#pragma unroll
    for (int kk = 0; kk < 16; ++kk) {
      float4 a = *(const float4*)&As[kk][ty*4];
      float4 b = *(const float4*)&Bs[kk][tx*4];
      acc[0][0] += a.x*b.x; acc[0][1] += a.x*b.y; acc[0][2] += a.x*b.z; acc[0][3] += a.x*b.w;
      acc[1][0] += a.y*b.x; acc[1][1] += a.y*b.y; acc[1][2] += a.y*b.z; acc[1][3] += a.y*b.w;
      acc[2][0] += a.z*b.x; acc[2][1] += a.z*b.y; acc[2][2] += a.z*b.z; acc[2][3] += a.z*b.w;
      acc[3][0] += a.w*b.x; acc[3][1] += a.w*b.y; acc[3][2] += a.w*b.z; acc[3][3] += a.w*b.w;
    }
  }
  const int nc = n0 + tx * 4;
  float4 bb = *(const float4*)&bias1[nc];
  if (bias2) {
    float4 b2 = *(const float4*)&bias2[nc];
    bb.x += b2.x; bb.y += b2.y; bb.z += b2.z; bb.w += b2.w;
  }
#pragma unroll
  for (int i = 0; i < 4; ++i) {
    const int m = m0 + ty * 4 + i;
    float4 o;
    o.x = acc[i][0] + bb.x; o.y = acc[i][1] + bb.y;
    o.z = acc[i][2] + bb.z; o.w = acc[i][3] + bb.w;
    if (gmode) {
      const int bi = m >> 9, tt = m & 511;
      const int g = nc >> 9, j = nc & 511;
      *(float4*)&C[((size_t)(tt * 4 + g) * 32 + bi) * 512 + j] = o;
    } else {
      *(float4*)&C[(size_t)m * N + nc] = o;
    }
  }
}

// ---------------------------------------------------------------------------
// Persistent 2-layer-callable LSTM recurrence.
// 256 WGs x 256 threads. WG wg owns hidden units j0=2*wg, j0+1 for all 32 batches.
// Whh slice (8 rows x 512) lives in REGISTERS (w_reg[16][4] per thread).
// h^t broadcast via transposed global buffer hT[2][512 j][32 b], staged to LDS.
// Grid sync: per-WG monotonic flags + agent-scope release/acquire.
// ---------------------------------------------------------------------------
__global__ __launch_bounds__(256) void lstm_rec(
    const float* __restrict__ G,     // [512 t][4 g][32 b][512 j]
    const float* __restrict__ Whh,   // [2048][512]
    float* __restrict__ Hout,        // [(b*512+t)*512 + j]
    float* __restrict__ hT,          // [2][512][32]
    int* __restrict__ flags,         // [256]
    int gen_base) {
  __shared__ float h_lds[512 * PADH];
  __shared__ float red2[4][8][36];
  __shared__ float gates_s[NBAT][2][4];

  const int tid = threadIdx.x;
  const int wg  = blockIdx.x;
  const int j0  = wg * 2;
  const int kq  = tid >> 3;         // [0,32)  k-interleave id
  const int bq  = (tid >> 1) & 3;   // [0,4)   batch octet
  const int jj  = tid & 1;
  const int b0  = bq * 8;
  const int wv  = tid >> 6;
  const int lane = tid & 63;

  // Whh slice into registers: w_reg[i][g] = Whh[g*512 + j0 + jj][kq + 32*i]
  float w_reg[16][4];
#pragma unroll
  for (int g = 0; g < 4; ++g) {
    const float* wrow = Whh + (size_t)(g * 512 + j0 + jj) * 512 + kq;
#pragma unroll
    for (int i = 0; i < 16; ++i) w_reg[i][g] = wrow[32 * i];
  }

  const int ob = tid >> 1;          // owner decode (valid for tid<64)
  const int ojj = tid & 1;
  const int oj = j0 + ojj;
  float c_reg = 0.f;

  for (int t = 0; t < 512; ++t) {
    const float* hcur = hT + (size_t)(t & 1) * (512 * NBAT);
    float* hnxt = hT + (size_t)((t + 1) & 1) * (512 * NBAT);

    // prefetch gate preactivations for this step (owners only)
    float pre0 = 0.f, pre1 = 0.f, pre2 = 0.f, pre3 = 0.f;
    if (tid < 64) {
      const size_t gb = ((size_t)(t * 4) * 32 + ob) * 512 + oj;
      pre0 = G[gb];
      pre1 = G[gb + (size_t)32 * 512];
      pre2 = G[gb + (size_t)64 * 512];
      pre3 = G[gb + (size_t)96 * 512];
    }

    // stage h^t into LDS as [k][b] with pad PADH
#pragma unroll
    for (int it = 0; it < 16; ++it) {
      const int p = tid * 4 + it * 1024;
      float4 v = *(const float4*)(hcur + p);
      const int k = p >> 5, bb = p & 31;
      float* dst = h_lds + k * PADH + bb;
      ((float2*)dst)[0] = make_float2(v.x, v.y);
      ((float2*)dst)[1] = make_float2(v.z, v.w);
    }
    __syncthreads();

    // compute: acc[bi][g] over 16 k's (k = kq + 32*i)
    float acc[8][4] = {};
#pragma unroll
    for (int i = 0; i < 16; ++i) {
      const int k = kq + 32 * i;
      const float* hp = h_lds + k * PADH + b0;
      float2 ha = ((const float2*)hp)[0];
      float2 hb = ((const float2*)hp)[1];
      float2 hc = ((const float2*)hp)[2];
      float2 hd = ((const float2*)hp)[3];
      float hv[8] = {ha.x, ha.y, hb.x, hb.y, hc.x, hc.y, hd.x, hd.y};
#pragma unroll
      for (int bi = 0; bi < 8; ++bi)
#pragma unroll
        for (int g = 0; g < 4; ++g)
          acc[bi][g] += hv[bi] * w_reg[i][g];
    }

    // in-wave reduce over the 8 kq's of this wave (lanes stride 8)
#pragma unroll
    for (int bi = 0; bi < 8; ++bi)
#pragma unroll
      for (int g = 0; g < 4; ++g) {
        float v = acc[bi][g];
        v += __shfl_down(v, 32, 64);
        v += __shfl_down(v, 16, 64);
        v += __shfl_down(v, 8, 64);
        acc[bi][g] = v;
      }
    if (lane < 8) {
      float* r = &red2[wv][lane][0];
#pragma unroll
      for (int e = 0; e < 32; ++e) r[e] = acc[e >> 2][e & 3];
    }
    __syncthreads();

    // cross-wave reduce + scatter to gates_s
    {
      const int grp = tid >> 5, e = tid & 31;
      float v = red2[0][grp][e] + red2[1][grp][e] + red2[2][grp][e] + red2[3][grp][e];
      gates_s[(grp >> 1) * 8 + (e >> 2)][grp & 1][e & 3] = v;
    }
    __syncthreads();

    // owners: LSTM cell update
    if (tid < 64) {
      const float gi = pre0 + gates_s[ob][ojj][0];
      const float gf = pre1 + gates_s[ob][ojj][1];
      const float gg = pre2 + gates_s[ob][ojj][2];
      const float go = pre3 + gates_s[ob][ojj][3];
      const float iv = sigf(gi);
      const float fv = sigf(gf);
      const float gv = tanhf(gg);
      const float ov = sigf(go);
      const float c = fv * c_reg + iv * gv;
      c_reg = c;
      const float h = ov * tanhf(c);
      Hout[((size_t)ob * 512 + t) * 512 + oj] = h;
      hnxt[oj * 32 + ob] = h;
    }

    // grid barrier (monotonic per-WG flags)
    __threadfence();
    __syncthreads();
    const int target = gen_base + t + 1;
    if (tid == 0)
      __hip_atomic_store(&flags[wg], target, __ATOMIC_RELEASE, __HIP_MEMORY_SCOPE_AGENT);
    while (__hip_atomic_load(&flags[tid], __ATOMIC_ACQUIRE, __HIP_MEMORY_SCOPE_AGENT) < target)
      __builtin_amdgcn_s_sleep(2);
    __syncthreads();
  }
}

// ---------------------------------------------------------------------------
// Fused attention: out[b,q] = (1/8) * sum_h softmax_{d<=q}(QK^T/8)[d] * H2[b,q,d]*Wo[d] + bo
// grid (32 qt, 32 b), 256 threads. Q in registers, K staged in XOR-swizzled LDS.
// ---------------------------------------------------------------------------
__device__ __forceinline__ int kswz(int row, int col) {
  return row * 64 + (col ^ (((row >> 2) & 7) << 2));
}

__global__ __launch_bounds__(256) void attn_kernel(
    const float* __restrict__ Qg, const float* __restrict__ Kg,
    const float* __restrict__ H2, const float* __restrict__ Wo,
    const float* __restrict__ bo, float* __restrict__ out) {
  __shared__ float Ks[64 * 64];
  __shared__ float part[4][16][68];
  __shared__ float s[16][512];
  __shared__ float Wo_s[512];

  const int tid = threadIdx.x;
  const int qt = blockIdx.x, b = blockIdx.y;
  const int q0 = qt * 16;
  const int dd = tid >> 6, qq = (tid >> 4) & 3, kq = tid & 15;
  const int srow = tid >> 4, slane = tid & 15;

  Wo_s[tid] = Wo[tid];
  Wo_s[256 + tid] = Wo[256 + tid];

  float out_reg = 0.f;
  const int kcmax = (q0 + 15) >> 6;

  for (int h = 0; h < 8; ++h) {
    // Q fragment into registers: rows q0+qq*4+r, dims h*64 + dd*16 + [0,16)
    float qreg[4][16];
#pragma unroll
    for (int r = 0; r < 4; ++r) {
      const float* qrow = Qg + ((size_t)(b * 512) + q0 + qq * 4 + r) * 512 + h * 64 + dd * 16;
#pragma unroll
      for (int i = 0; i < 16; i += 4) {
        float4 v = *(const float4*)(qrow + i);
        qreg[r][i] = v.x; qreg[r][i+1] = v.y; qreg[r][i+2] = v.z; qreg[r][i+3] = v.w;
      }
    }

    for (int kc = 0; kc <= kcmax; ++kc) {
      __syncthreads();  // Ks/part reuse; also protects s vs prev-head softmax
      // stage K chunk [64 keys][64 d] transposed to Ks[d][kk] (XOR swizzle)
#pragma unroll
      for (int it = 0; it < 4; ++it) {
        const int f = tid * 4 + it * 1024;
        const int kk = f >> 6, d = f & 63;
        float4 v = *(const float4*)(Kg + ((size_t)(b * 512) + kc * 64 + kk) * 512 + h * 64 + d);
        Ks[kswz(d + 0, kk)] = v.x;
        Ks[kswz(d + 1, kk)] = v.y;
        Ks[kswz(d + 2, kk)] = v.z;
        Ks[kswz(d + 3, kk)] = v.w;
      }
      __syncthreads();

      float acc[4][4] = {};
#pragma unroll
      for (int i = 0; i < 16; ++i) {
        const int row = dd * 16 + i;
        float4 k4 = *(const float4*)&Ks[kswz(row, kq * 4)];
#pragma unroll
        for (int r = 0; r < 4; ++r) {
          acc[r][0] += qreg[r][i] * k4.x;
          acc[r][1] += qreg[r][i] * k4.y;
          acc[r][2] += qreg[r][i] * k4.z;
          acc[r][3] += qreg[r][i] * k4.w;
        }
      }
#pragma unroll
      for (int r = 0; r < 4; ++r) {
        float4 o = make_float4(acc[r][0], acc[r][1], acc[r][2], acc[r][3]);
        *(float4*)&part[dd][qq * 4 + r][kq * 4] = o;
      }
      __syncthreads();
      {
        const int qi = tid >> 4, c = tid & 15;
        float4 p0 = *(const float4*)&part[0][qi][c * 4];
        float4 p1 = *(const float4*)&part[1][qi][c * 4];
        float4 p2 = *(const float4*)&part[2][qi][c * 4];
        float4 p3 = *(const float4*)&part[3][qi][c * 4];
        float4 r;
        r.x = ((p0.x + p1.x) + (p2.x + p3.x)) * 0.125f;
        r.y = ((p0.y + p1.y) + (p2.y + p3.y)) * 0.125f;
        r.z = ((p0.z + p1.z) + (p2.z + p3.z)) * 0.125f;
        r.w = ((p0.w + p1.w) + (p2.w + p3.w)) * 0.125f;
        *(float4*)&s[qi][kc * 64 + c * 4] = r;
      }
    }
    __syncthreads();

    // masked softmax + fused (H2*Wo) dot for row srow
    const int q = q0 + srow;
    const int count = q + 1;
    const float* sp = &s[srow][0];
    float m = -1e30f;
    for (int d = slane; d < count; d += 16) m = fmaxf(m, sp[d]);
    m = fmaxf(m, __shfl_xor(m, 1, 64));
    m = fmaxf(m, __shfl_xor(m, 2, 64));
    m = fmaxf(m, __shfl_xor(m, 4, 64));
    m = fmaxf(m, __shfl_xor(m, 8, 64));
    float z = 0.f, zw = 0.f;
    const float* h2row = H2 + ((size_t)(b * 512) + q) * 512;
    for (int d = slane; d < count; d += 16) {
      const float e = __expf(sp[d] - m);
      z += e;
      zw += e * h2row[d] * Wo_s[d];
    }
    z += __shfl_xor(z, 1, 64); z += __shfl_xor(z, 2, 64);
    z += __shfl_xor(z, 4, 64); z += __shfl_xor(z, 8, 64);
    zw += __shfl_xor(zw, 1, 64); zw += __shfl_xor(zw, 2, 64);
    zw += __shfl_xor(zw, 4, 64); zw += __shfl_xor(zw, 8, 64);
    out_reg += zw / z;
    __syncthreads();
  }

  if (slane == 0)
    out[b * 512 + q0 + srow] = out_reg * 0.125f + bo[0];
}

// ---------------------------------------------------------------------------
extern "C" void kernel_launch(void* const* d_in, const int* in_sizes, int n_in,
                              void* d_out, int out_size, void* d_ws, size_t ws_size,
                              hipStream_t stream) {
  const float* x    = (const float*)d_in[0];
  const float* Wih0 = (const float*)d_in[1];
  const float* Whh0 = (const float*)d_in[2];
  const float* bih0 = (const float*)d_in[3];
  const float* bhh0 = (const float*)d_in[4];
  const float* Wih1 = (const float*)d_in[5];
  const float* Whh1 = (const float*)d_in[6];
  const float* bih1 = (const float*)d_in[7];
  const float* bhh1 = (const float*)d_in[8];
  const float* Wq   = (const float*)d_in[9];
  const float* bq   = (const float*)d_in[10];
  const float* Wk   = (const float*)d_in[11];
  const float* bk   = (const float*)d_in[12];
  const float* Wo   = (const float*)d_in[13];
  const float* bo   = (const float*)d_in[14];
  float* out = (float*)d_out;

  float* ws = (float*)d_ws;
  const size_t M = 16384;
  float* G  = ws;                                  // 16384*2048 = 33,554,432 f
  float* H1 = G  + (size_t)16384 * 2048;           //  8,388,608 f
  float* H2 = H1 + (size_t)16384 * 512;            //  8,388,608 f
  float* hT = H2 + (size_t)16384 * 512;            //     32,768 f
  int* flags = (int*)(hT + 2 * 16384);             //        256 i
  // Q/K reuse dead regions: Qb over H1 (dead after G1 gemm), Kb over G (dead after rec1)
  float* Qb = H1;
  float* Kb = G;

  // zero h state + flags (every call; re-zeroed under graph replay)
  hipMemsetAsync(hT, 0, (2 * 16384) * sizeof(float) + 256 * sizeof(int), stream);

  // layer 0: G = x @ Wih0^T + bih0 + bhh0  (G layout), then recurrence
  gemm64<<<dim3(2048 / 64, M / 64), 256, 0, stream>>>(x, Wih0, bih0, bhh0, G,
                                                      (int)M, 2048, 256, 1);
  lstm_rec<<<256, 256, 0, stream>>>(G, Whh0, H1, hT, flags, 0);

  // layer 1
  hipMemsetAsync(hT, 0, (2 * 16384) * sizeof(float), stream);
  gemm64<<<dim3(2048 / 64, M / 64), 256, 0, stream>>>(H1, Wih1, bih1, bhh1, G,
                                                      (int)M, 2048, 512, 1);
  lstm_rec<<<256, 256, 0, stream>>>(G, Whh1, H2, hT, flags, 512);

  // Q/K projections (plain row-major [B*L][512])
  gemm64<<<dim3(512 / 64, M / 64), 256, 0, stream>>>(H2, Wq, bq, nullptr, Qb,
                                                     (int)M, 512, 512, 0);
  gemm64<<<dim3(512 / 64, M / 64), 256, 0, stream>>>(H2, Wk, bk, nullptr, Kb,
                                                     (int)M, 512, 512, 0);

  // fused causal attention + head-mean + gated linear output
  attn_kernel<<<dim3(32, 32), 256, 0, stream>>>(Qb, Kb, H2, Wo, bo, out);
}

// Round 2
// 15335.614 us; speedup vs baseline: 3.1460x; 3.1460x over previous
//
#include <hip/hip_runtime.h>
#include <cmath>

#define NBAT 32
#define PADH 36   // h_lds row pad (floats): keeps float4 stores 16B-aligned, 2-way reads

__device__ __forceinline__ float sigf(float x) { return 1.f / (1.f + __expf(-x)); }

// ---------------------------------------------------------------------------
// GEMM: C[M,N] = A[M,K] @ B[N,K]^T + bias1 (+ bias2), 128x128 tile, 8x8/thread
// gmode=1: scatter-store into G layout [t][g][b][j] (row m = b*512+t, col n = g*512+j)
// ---------------------------------------------------------------------------
__global__ __launch_bounds__(256, 2) void gemm128(
    const float* __restrict__ A, const float* __restrict__ B,
    const float* __restrict__ bias1, const float* __restrict__ bias2,
    float* __restrict__ C, int M, int N, int K, int gmode) {
  __shared__ __align__(16) float As[8][132];
  __shared__ __align__(16) float Bs[8][132];
  const int tid = threadIdx.x;
  const int n0 = blockIdx.x * 128, m0 = blockIdx.y * 128;
  const int lm = tid & 127, kh = tid >> 7;   // staging: row, k-half
  const int tx = tid & 15, ty = tid >> 4;    // compute: col group, row group
  const float* Ap = A + (size_t)(m0 + lm) * K + kh * 4;
  const float* Bp = B + (size_t)(n0 + lm) * K + kh * 4;
  float acc[8][8] = {};
  float4 av = *(const float4*)Ap;
  float4 bv = *(const float4*)Bp;
  const int nk = K / 8;
  for (int kt = 0; kt < nk; ++kt) {
    __syncthreads();
    As[kh*4+0][lm] = av.x; As[kh*4+1][lm] = av.y;
    As[kh*4+2][lm] = av.z; As[kh*4+3][lm] = av.w;
    Bs[kh*4+0][lm] = bv.x; Bs[kh*4+1][lm] = bv.y;
    Bs[kh*4+2][lm] = bv.z; Bs[kh*4+3][lm] = bv.w;
    __syncthreads();
    if (kt + 1 < nk) {
      av = *(const float4*)(Ap + (kt + 1) * 8);
      bv = *(const float4*)(Bp + (kt + 1) * 8);
    }
#pragma unroll
    for (int kk = 0; kk < 8; ++kk) {
      float4 a0 = *(const float4*)&As[kk][ty*8];
      float4 a1 = *(const float4*)&As[kk][ty*8+4];
      float4 b0 = *(const float4*)&Bs[kk][tx*8];
      float4 b1 = *(const float4*)&Bs[kk][tx*8+4];
      float ar[8] = {a0.x,a0.y,a0.z,a0.w,a1.x,a1.y,a1.z,a1.w};
      float br[8] = {b0.x,b0.y,b0.z,b0.w,b1.x,b1.y,b1.z,b1.w};
#pragma unroll
      for (int i = 0; i < 8; ++i)
#pragma unroll
        for (int j = 0; j < 8; ++j)
          acc[i][j] += ar[i] * br[j];
    }
  }
  const int nc = n0 + tx * 8;
  float bb[8];
  { float4 c0 = *(const float4*)&bias1[nc], c1 = *(const float4*)&bias1[nc+4];
    bb[0]=c0.x; bb[1]=c0.y; bb[2]=c0.z; bb[3]=c0.w;
    bb[4]=c1.x; bb[5]=c1.y; bb[6]=c1.z; bb[7]=c1.w; }
  if (bias2) {
    float4 c0 = *(const float4*)&bias2[nc], c1 = *(const float4*)&bias2[nc+4];
    bb[0]+=c0.x; bb[1]+=c0.y; bb[2]+=c0.z; bb[3]+=c0.w;
    bb[4]+=c1.x; bb[5]+=c1.y; bb[6]+=c1.z; bb[7]+=c1.w;
  }
#pragma unroll
  for (int i = 0; i < 8; ++i) {
    const int m = m0 + ty * 8 + i;
    float4 o0 = make_float4(acc[i][0]+bb[0], acc[i][1]+bb[1], acc[i][2]+bb[2], acc[i][3]+bb[3]);
    float4 o1 = make_float4(acc[i][4]+bb[4], acc[i][5]+bb[5], acc[i][6]+bb[6], acc[i][7]+bb[7]);
    if (gmode) {
      const int b = m >> 9, tt = m & 511, g = nc >> 9, j = nc & 511;
      const size_t base = ((size_t)(tt * 4 + g) * 32 + b) * 512 + j;
      *(float4*)&C[base] = o0; *(float4*)&C[base + 4] = o1;
    } else {
      *(float4*)&C[(size_t)m * N + nc] = o0;
      *(float4*)&C[(size_t)m * N + nc + 4] = o1;
    }
  }
}

// ---------------------------------------------------------------------------
// Persistent LSTM recurrence. 128 WGs x 256 threads; WG owns 4 hidden units
// (j0=4*wg) for all 32 batches. Whh slice (16 rows x 512) in registers
// (w_reg[32][4]). Barrier: wave0-only relaxed polling + single acquire fence;
// producers (waves 0,1) release-fence + relaxed flag store (2 flags/WG).
// ---------------------------------------------------------------------------
__global__ __launch_bounds__(256, 1) void lstm_rec(
    const float* __restrict__ G,     // [512 t][4 g][32 b][512 j]
    const float* __restrict__ Whh,   // [2048][512]
    float* __restrict__ Hout,        // [(b*512+t)*512 + j]
    float* __restrict__ hT,          // [2][512 j][32 b]
    int* __restrict__ flags,         // [256] (2 per WG)
    int gen_base) {
  __shared__ __align__(16) float h_lds[512 * PADH];
  __shared__ __align__(16) float red2[4][16][36];
  __shared__ __align__(16) float pre_s[2][4][32][4];

  const int tid = threadIdx.x;
  const int wg  = blockIdx.x;
  const int j0  = wg * 4;
  const int lane = tid & 63;
  const int wv   = tid >> 6;

  // compute decode
  const int kq = tid >> 4;          // [0,16): k-slice (wave w covers 4w..4w+3)
  const int jj = tid & 3;           // [0,4)
  const int bq = (tid >> 2) & 3;    // [0,4)
  const int b0 = bq * 8;

  // Whh slice into registers: w_reg[i][g] = Whh[g*512 + j0 + jj][kq + 16*i]
  float w_reg[32][4];
#pragma unroll
  for (int g = 0; g < 4; ++g) {
    const float* wrow = Whh + (size_t)(g * 512 + j0 + jj) * 512 + kq;
#pragma unroll
    for (int i = 0; i < 32; ++i) w_reg[i][g] = wrow[16 * i];
  }

  // owner decode (tid < 128): one (batch, j) output per thread
  const int ob  = tid >> 2;         // [0,32)
  const int ojj = tid & 3;          // [0,4)
  const int rl  = (ob >> 3) * 4 + ojj;  // red2 l-index = bq*4+jj
  const int rbl = ob & 7;               // b_local
  float c_reg = 0.f;

  for (int t = 0; t < 512; ++t) {
    const int buf = t & 1;

    // waves 2,3: prefetch this step's gate preactivations into LDS
    if (tid >= 128) {
      const int pid = tid - 128;
      const int pg = pid >> 5, pb = pid & 31;
      float4 v = *(const float4*)&G[(((size_t)t * 4 + pg) * 32 + pb) * 512 + j0];
      *(float4*)&pre_s[buf][pg][pb][0] = v;
    }

    // wave 0: poll flags (relaxed, no cache maintenance), then one acquire fence
    if (tid < 64) {
      const int target = gen_base + t;
      for (;;) {
        int f0 = __hip_atomic_load(&flags[lane],       __ATOMIC_RELAXED, __HIP_MEMORY_SCOPE_AGENT);
        int f1 = __hip_atomic_load(&flags[lane + 64],  __ATOMIC_RELAXED, __HIP_MEMORY_SCOPE_AGENT);
        int f2 = __hip_atomic_load(&flags[lane + 128], __ATOMIC_RELAXED, __HIP_MEMORY_SCOPE_AGENT);
        int f3 = __hip_atomic_load(&flags[lane + 192], __ATOMIC_RELAXED, __HIP_MEMORY_SCOPE_AGENT);
        bool ok = (f0 >= target) && (f1 >= target) && (f2 >= target) && (f3 >= target);
        if (__all(ok)) break;
        __builtin_amdgcn_s_sleep(1);
      }
      __builtin_amdgcn_fence(__ATOMIC_ACQUIRE, "agent");
    }
    __syncthreads();

    // stage h^t into LDS as [k][b], pad PADH
    const float* hcur = hT + (size_t)buf * (512 * NBAT);
#pragma unroll
    for (int it = 0; it < 16; ++it) {
      const int p = tid * 4 + it * 1024;
      float4 v = *(const float4*)(hcur + p);
      const int k = p >> 5, bb = p & 31;
      *(float4*)&h_lds[k * PADH + bb] = v;
    }
    __syncthreads();

    // FMA: acc[8 b][4 g] over 32 k's (k = kq + 16*i)
    float acc[8][4] = {};
#pragma unroll
    for (int i = 0; i < 32; ++i) {
      const int k = kq + 16 * i;
      const float* hp = &h_lds[k * PADH + b0];
      float4 h0 = *(const float4*)hp;
      float4 h1 = *(const float4*)(hp + 4);
      float hv[8] = {h0.x, h0.y, h0.z, h0.w, h1.x, h1.y, h1.z, h1.w};
#pragma unroll
      for (int bi = 0; bi < 8; ++bi)
#pragma unroll
        for (int g = 0; g < 4; ++g)
          acc[bi][g] += hv[bi] * w_reg[i][g];
    }

    // wave-local reduce over 4 kq groups (lane bits 4,5)
#pragma unroll
    for (int bi = 0; bi < 8; ++bi)
#pragma unroll
      for (int g = 0; g < 4; ++g) {
        float v = acc[bi][g];
        v += __shfl_down(v, 32, 64);
        v += __shfl_down(v, 16, 64);
        acc[bi][g] = v;
      }
    if (lane < 16) {
#pragma unroll
      for (int e = 0; e < 32; ++e) red2[wv][lane][e] = acc[e >> 2][e & 3];
    }
    __syncthreads();

    // owners (tid<128): cross-wave combine + LSTM cell update
    if (tid < 128) {
      float4 s0 = *(const float4*)&red2[0][rl][rbl * 4];
      float4 s1 = *(const float4*)&red2[1][rl][rbl * 4];
      float4 s2 = *(const float4*)&red2[2][rl][rbl * 4];
      float4 s3 = *(const float4*)&red2[3][rl][rbl * 4];
      const float gi = (s0.x + s1.x) + (s2.x + s3.x) + pre_s[buf][0][ob][ojj];
      const float gf = (s0.y + s1.y) + (s2.y + s3.y) + pre_s[buf][1][ob][ojj];
      const float gg = (s0.z + s1.z) + (s2.z + s3.z) + pre_s[buf][2][ob][ojj];
      const float go = (s0.w + s1.w) + (s2.w + s3.w) + pre_s[buf][3][ob][ojj];
      const float iv = sigf(gi);
      const float fv = sigf(gf);
      const float gv = tanhf(gg);
      const float ov = sigf(go);
      const float c = fv * c_reg + iv * gv;
      c_reg = c;
      const float h = ov * tanhf(c);
      float* hnxt = hT + (size_t)((t + 1) & 1) * (512 * NBAT);
      hnxt[(j0 + ojj) * 32 + ob] = h;
      Hout[((size_t)ob * 512 + t) * 512 + j0 + ojj] = h;
      __builtin_amdgcn_fence(__ATOMIC_RELEASE, "agent");
      if ((tid & 63) == 0)
        __hip_atomic_store(&flags[wg * 2 + wv], gen_base + t + 1,
                           __ATOMIC_RELAXED, __HIP_MEMORY_SCOPE_AGENT);
    }
  }
}

// ---------------------------------------------------------------------------
// Fused attention: out[b,q] = (1/8)*sum_h softmax_{d<=q}(QK^T/8)[d]*H2[b,q,d]*Wo[d] + bo
// ---------------------------------------------------------------------------
__device__ __forceinline__ int kswz(int row, int col) {
  return row * 64 + (col ^ (((row >> 2) & 7) << 2));
}

__global__ __launch_bounds__(256) void attn_kernel(
    const float* __restrict__ Qg, const float* __restrict__ Kg,
    const float* __restrict__ H2, const float* __restrict__ Wo,
    const float* __restrict__ bo, float* __restrict__ out) {
  __shared__ float Ks[64 * 64];
  __shared__ float part[4][16][68];
  __shared__ float s[16][512];
  __shared__ float Wo_s[512];

  const int tid = threadIdx.x;
  const int qt = blockIdx.x, b = blockIdx.y;
  const int q0 = qt * 16;
  const int dd = tid >> 6, qq = (tid >> 4) & 3, kq = tid & 15;
  const int srow = tid >> 4, slane = tid & 15;

  Wo_s[tid] = Wo[tid];
  Wo_s[256 + tid] = Wo[256 + tid];

  float out_reg = 0.f;
  const int kcmax = (q0 + 15) >> 6;

  for (int h = 0; h < 8; ++h) {
    float qreg[4][16];
#pragma unroll
    for (int r = 0; r < 4; ++r) {
      const float* qrow = Qg + ((size_t)(b * 512) + q0 + qq * 4 + r) * 512 + h * 64 + dd * 16;
#pragma unroll
      for (int i = 0; i < 16; i += 4) {
        float4 v = *(const float4*)(qrow + i);
        qreg[r][i] = v.x; qreg[r][i+1] = v.y; qreg[r][i+2] = v.z; qreg[r][i+3] = v.w;
      }
    }

    for (int kc = 0; kc <= kcmax; ++kc) {
      __syncthreads();
#pragma unroll
      for (int it = 0; it < 4; ++it) {
        const int f = tid * 4 + it * 1024;
        const int kk = f >> 6, d = f & 63;
        float4 v = *(const float4*)(Kg + ((size_t)(b * 512) + kc * 64 + kk) * 512 + h * 64 + d);
        Ks[kswz(d + 0, kk)] = v.x;
        Ks[kswz(d + 1, kk)] = v.y;
        Ks[kswz(d + 2, kk)] = v.z;
        Ks[kswz(d + 3, kk)] = v.w;
      }
      __syncthreads();

      float acc[4][4] = {};
#pragma unroll
      for (int i = 0; i < 16; ++i) {
        const int row = dd * 16 + i;
        float4 k4 = *(const float4*)&Ks[kswz(row, kq * 4)];
#pragma unroll
        for (int r = 0; r < 4; ++r) {
          acc[r][0] += qreg[r][i] * k4.x;
          acc[r][1] += qreg[r][i] * k4.y;
          acc[r][2] += qreg[r][i] * k4.z;
          acc[r][3] += qreg[r][i] * k4.w;
        }
      }
#pragma unroll
      for (int r = 0; r < 4; ++r)
        *(float4*)&part[dd][qq * 4 + r][kq * 4] =
            make_float4(acc[r][0], acc[r][1], acc[r][2], acc[r][3]);
      __syncthreads();
      {
        const int qi = tid >> 4, c = tid & 15;
        float4 p0 = *(const float4*)&part[0][qi][c * 4];
        float4 p1 = *(const float4*)&part[1][qi][c * 4];
        float4 p2 = *(const float4*)&part[2][qi][c * 4];
        float4 p3 = *(const float4*)&part[3][qi][c * 4];
        float4 r;
        r.x = ((p0.x + p1.x) + (p2.x + p3.x)) * 0.125f;
        r.y = ((p0.y + p1.y) + (p2.y + p3.y)) * 0.125f;
        r.z = ((p0.z + p1.z) + (p2.z + p3.z)) * 0.125f;
        r.w = ((p0.w + p1.w) + (p2.w + p3.w)) * 0.125f;
        *(float4*)&s[qi][kc * 64 + c * 4] = r;
      }
    }
    __syncthreads();

    const int q = q0 + srow;
    const int count = q + 1;
    const float* sp = &s[srow][0];
    float m = -1e30f;
    for (int d = slane; d < count; d += 16) m = fmaxf(m, sp[d]);
    m = fmaxf(m, __shfl_xor(m, 1, 64));
    m = fmaxf(m, __shfl_xor(m, 2, 64));
    m = fmaxf(m, __shfl_xor(m, 4, 64));
    m = fmaxf(m, __shfl_xor(m, 8, 64));
    float z = 0.f, zw = 0.f;
    const float* h2row = H2 + ((size_t)(b * 512) + q) * 512;
    for (int d = slane; d < count; d += 16) {
      const float e = __expf(sp[d] - m);
      z += e;
      zw += e * h2row[d] * Wo_s[d];
    }
    z += __shfl_xor(z, 1, 64); z += __shfl_xor(z, 2, 64);
    z += __shfl_xor(z, 4, 64); z += __shfl_xor(z, 8, 64);
    zw += __shfl_xor(zw, 1, 64); zw += __shfl_xor(zw, 2, 64);
    zw += __shfl_xor(zw, 4, 64); zw += __shfl_xor(zw, 8, 64);
    out_reg += zw / z;
    __syncthreads();
  }

  if (slane == 0)
    out[b * 512 + q0 + srow] = out_reg * 0.125f + bo[0];
}

// ---------------------------------------------------------------------------
extern "C" void kernel_launch(void* const* d_in, const int* in_sizes, int n_in,
                              void* d_out, int out_size, void* d_ws, size_t ws_size,
                              hipStream_t stream) {
  const float* x    = (const float*)d_in[0];
  const float* Wih0 = (const float*)d_in[1];
  const float* Whh0 = (const float*)d_in[2];
  const float* bih0 = (const float*)d_in[3];
  const float* bhh0 = (const float*)d_in[4];
  const float* Wih1 = (const float*)d_in[5];
  const float* Whh1 = (const float*)d_in[6];
  const float* bih1 = (const float*)d_in[7];
  const float* bhh1 = (const float*)d_in[8];
  const float* Wq   = (const float*)d_in[9];
  const float* bq   = (const float*)d_in[10];
  const float* Wk   = (const float*)d_in[11];
  const float* bk   = (const float*)d_in[12];
  const float* Wo   = (const float*)d_in[13];
  const float* bo   = (const float*)d_in[14];
  float* out = (float*)d_out;

  float* ws = (float*)d_ws;
  const size_t M = 16384;
  float* G  = ws;                                  // 16384*2048
  float* H1 = G  + (size_t)16384 * 2048;           // 16384*512
  float* H2 = H1 + (size_t)16384 * 512;            // 16384*512
  float* hT = H2 + (size_t)16384 * 512;            // 2*16384
  int* flags = (int*)(hT + 2 * 16384);             // 256
  float* Qb = H1;   // reuse (H1 dead after layer-1 G gemm)
  float* Kb = G;    // reuse (G dead after layer-1 recurrence)

  hipMemsetAsync(hT, 0, (2 * 16384) * sizeof(float) + 256 * sizeof(int), stream);

  // layer 0
  gemm128<<<dim3(2048 / 128, M / 128), 256, 0, stream>>>(x, Wih0, bih0, bhh0, G,
                                                         (int)M, 2048, 256, 1);
  lstm_rec<<<128, 256, 0, stream>>>(G, Whh0, H1, hT, flags, 0);

  // layer 1
  hipMemsetAsync(hT, 0, (2 * 16384) * sizeof(float), stream);
  gemm128<<<dim3(2048 / 128, M / 128), 256, 0, stream>>>(H1, Wih1, bih1, bhh1, G,
                                                         (int)M, 2048, 512, 1);
  lstm_rec<<<128, 256, 0, stream>>>(G, Whh1, H2, hT, flags, 512);

  // Q/K projections
  gemm128<<<dim3(512 / 128, M / 128), 256, 0, stream>>>(H2, Wq, bq, nullptr, Qb,
                                                        (int)M, 512, 512, 0);
  gemm128<<<dim3(512 / 128, M / 128), 256, 0, stream>>>(H2, Wk, bk, nullptr, Kb,
                                                        (int)M, 512, 512, 0);

  // fused causal attention + head-mean + gated output
  attn_kernel<<<dim3(32, 32), 256, 0, stream>>>(Qb, Kb, H2, Wo, bo, out);
}

// Round 6
// 9905.588 us; speedup vs baseline: 4.8705x; 1.5482x over previous
//
#include <hip/hip_runtime.h>
#include <cmath>

#define NBAT 32
#define PADH 36   // h_lds row pad (floats)

__device__ __forceinline__ float sigf(float x) { return 1.f / (1.f + __expf(-x)); }

// ---------------------------------------------------------------------------
// GEMM: C[M,N] = A[M,K] @ B[N,K]^T + bias1 (+ bias2), 128x128 tile, 8x8/thread
// gmode=1: scatter-store into G layout [t][g][b][j] (row m = b*512+t, col n = g*512+j)
// ---------------------------------------------------------------------------
__global__ __launch_bounds__(256, 2) void gemm128(
    const float* __restrict__ A, const float* __restrict__ B,
    const float* __restrict__ bias1, const float* __restrict__ bias2,
    float* __restrict__ C, int M, int N, int K, int gmode) {
  __shared__ __align__(16) float As[8][132];
  __shared__ __align__(16) float Bs[8][132];
  const int tid = threadIdx.x;
  const int n0 = blockIdx.x * 128, m0 = blockIdx.y * 128;
  const int lm = tid & 127, kh = tid >> 7;   // staging: row, k-half
  const int tx = tid & 15, ty = tid >> 4;    // compute: col group, row group
  const float* Ap = A + (size_t)(m0 + lm) * K + kh * 4;
  const float* Bp = B + (size_t)(n0 + lm) * K + kh * 4;
  float acc[8][8] = {};
  float4 av = *(const float4*)Ap;
  float4 bv = *(const float4*)Bp;
  const int nk = K / 8;
  for (int kt = 0; kt < nk; ++kt) {
    __syncthreads();
    As[kh*4+0][lm] = av.x; As[kh*4+1][lm] = av.y;
    As[kh*4+2][lm] = av.z; As[kh*4+3][lm] = av.w;
    Bs[kh*4+0][lm] = bv.x; Bs[kh*4+1][lm] = bv.y;
    Bs[kh*4+2][lm] = bv.z; Bs[kh*4+3][lm] = bv.w;
    __syncthreads();
    if (kt + 1 < nk) {
      av = *(const float4*)(Ap + (kt + 1) * 8);
      bv = *(const float4*)(Bp + (kt + 1) * 8);
    }
#pragma unroll
    for (int kk = 0; kk < 8; ++kk) {
      float4 a0 = *(const float4*)&As[kk][ty*8];
      float4 a1 = *(const float4*)&As[kk][ty*8+4];
      float4 b0 = *(const float4*)&Bs[kk][tx*8];
      float4 b1 = *(const float4*)&Bs[kk][tx*8+4];
      float ar[8] = {a0.x,a0.y,a0.z,a0.w,a1.x,a1.y,a1.z,a1.w};
      float br[8] = {b0.x,b0.y,b0.z,b0.w,b1.x,b1.y,b1.z,b1.w};
#pragma unroll
      for (int i = 0; i < 8; ++i)
#pragma unroll
        for (int j = 0; j < 8; ++j)
          acc[i][j] += ar[i] * br[j];
    }
  }
  const int nc = n0 + tx * 8;
  float bb[8];
  { float4 c0 = *(const float4*)&bias1[nc], c1 = *(const float4*)&bias1[nc+4];
    bb[0]=c0.x; bb[1]=c0.y; bb[2]=c0.z; bb[3]=c0.w;
    bb[4]=c1.x; bb[5]=c1.y; bb[6]=c1.z; bb[7]=c1.w; }
  if (bias2) {
    float4 c0 = *(const float4*)&bias2[nc], c1 = *(const float4*)&bias2[nc+4];
    bb[0]+=c0.x; bb[1]+=c0.y; bb[2]+=c0.z; bb[3]+=c0.w;
    bb[4]+=c1.x; bb[5]+=c1.y; bb[6]+=c1.z; bb[7]+=c1.w;
  }
#pragma unroll
  for (int i = 0; i < 8; ++i) {
    const int m = m0 + ty * 8 + i;
    float4 o0 = make_float4(acc[i][0]+bb[0], acc[i][1]+bb[1], acc[i][2]+bb[2], acc[i][3]+bb[3]);
    float4 o1 = make_float4(acc[i][4]+bb[4], acc[i][5]+bb[5], acc[i][6]+bb[6], acc[i][7]+bb[7]);
    if (gmode) {
      const int b = m >> 9, tt = m & 511, g = nc >> 9, j = nc & 511;
      const size_t base = ((size_t)(tt * 4 + g) * 32 + b) * 512 + j;
      *(float4*)&C[base] = o0; *(float4*)&C[base + 4] = o1;
    } else {
      *(float4*)&C[(size_t)m * N + nc] = o0;
      *(float4*)&C[(size_t)m * N + nc + 4] = o1;
    }
  }
}

// ---------------------------------------------------------------------------
// Persistent LSTM recurrence, fence-free cross-WG sync via sc0 sc1 (L1+L2
// bypass; LLC = agent coherence point). No buffer_inv / buffer_wbl2 in loop.
// Producer: h store (sc0 sc1) -> s_waitcnt vmcnt(0) -> flag store (sc0 sc1).
// Consumer: wave0 polls flags (sc0 sc1) -> barrier -> FULL-coverage staging:
// 256 thr x 16 float4 = 4096 float4 = 16384 floats (all 512 k rows). This was
// the rounds-3..5 bug: staging covered only half of h.
// G preactivations prefetched ONE STEP AHEAD by waves 2,3 (double-buffered).
// ---------------------------------------------------------------------------
__global__ __launch_bounds__(256, 1) void lstm_rec(
    const float* __restrict__ G,     // [512 t][4 g][32 b][512 j]
    const float* __restrict__ Whh,   // [2048][512]
    float* __restrict__ Hout,        // [(b*512+t)*512 + j]
    float* __restrict__ hT,          // [2][512 j][32 b]
    int* __restrict__ flags,         // [256] (2 per WG)
    int gen_base) {
  __shared__ __align__(16) float h_lds[512 * PADH];
  __shared__ __align__(16) float red2[4][16][36];
  __shared__ __align__(16) float pre_s[2][4][32][4];

  const int tid = threadIdx.x;
  const int wg  = blockIdx.x;
  const int j0  = wg * 4;
  const int lane = tid & 63;
  const int wv   = tid >> 6;

  // compute decode
  const int kq = tid >> 4;          // [0,16): k-slice
  const int jj = tid & 3;           // [0,4)
  const int bq = (tid >> 2) & 3;    // [0,4)
  const int b0 = bq * 8;

  // Whh slice into registers: w_reg[i][g] = Whh[g*512 + j0 + jj][kq + 16*i]
  float w_reg[32][4];
#pragma unroll
  for (int g = 0; g < 4; ++g) {
    const float* wrow = Whh + (size_t)(g * 512 + j0 + jj) * 512 + kq;
#pragma unroll
    for (int i = 0; i < 32; ++i) w_reg[i][g] = wrow[16 * i];
  }

  // owner decode (tid < 128)
  const int ob  = tid >> 2;             // [0,32)
  const int ojj = tid & 3;              // [0,4)
  const int rl  = (ob >> 3) * 4 + ojj;  // red2 l-index
  const int rbl = ob & 7;               // b_local
  float c_reg = 0.f;

  // G prefetch decode (waves 2,3)
  const int pid = tid - 128;
  const int pg = pid >> 5, pb = pid & 31;
  float4 gpre;
  if (tid >= 128)
    gpre = *(const float4*)&G[(((size_t)0 * 4 + pg) * 32 + pb) * 512 + j0];

  for (int t = 0; t < 512; ++t) {
    const int buf = t & 1;

    // waves 2,3: commit prefetched G(t) to LDS; issue loads for t+1
    if (tid >= 128) {
      *(float4*)&pre_s[buf][pg][pb][0] = gpre;
      if (t + 1 < 512)
        gpre = *(const float4*)&G[(((size_t)(t + 1) * 4 + pg) * 32 + pb) * 512 + j0];
    }

    // wave 0: poll flags through LLC (sc0 sc1 loads, batched, one waitcnt)
    if (tid < 64) {
      const int target = gen_base + t;
      const int* fp = flags + lane;
      for (;;) {
        int f0, f1, f2, f3;
        asm volatile(
            "global_load_dword %0, %4, off sc0 sc1\n\t"
            "global_load_dword %1, %5, off sc0 sc1\n\t"
            "global_load_dword %2, %6, off sc0 sc1\n\t"
            "global_load_dword %3, %7, off sc0 sc1\n\t"
            "s_waitcnt vmcnt(0)"
            : "=&v"(f0), "=&v"(f1), "=&v"(f2), "=&v"(f3)
            : "v"(fp), "v"(fp + 64), "v"(fp + 128), "v"(fp + 192)
            : "memory");
        if (__all((f0 >= target) && (f1 >= target) && (f2 >= target) && (f3 >= target)))
          break;
        __builtin_amdgcn_s_sleep(1);
      }
    }
    __syncthreads();

    // stage h^t into LDS as [k][b] — FULL coverage: 256 thr x 16 float4 =
    // 16384 floats (512 rows x 32 batches).
    {
      const float* hcur = hT + (size_t)buf * (512 * NBAT);
      float4 hv[16];
#pragma unroll
      for (int it = 0; it < 16; ++it)
        asm volatile("global_load_dwordx4 %0, %1, off sc0 sc1"
                     : "=&v"(hv[it]) : "v"(hcur + (size_t)(tid + it * 256) * 4));
      asm volatile("s_waitcnt vmcnt(0)" ::: "memory");
      __builtin_amdgcn_sched_barrier(0);
#pragma unroll
      for (int it = 0; it < 16; ++it) {
        const int idx4 = tid + it * 256;                 // [0,4096)
        *(float4*)&h_lds[(idx4 >> 3) * PADH + (idx4 & 7) * 4] = hv[it];
      }
    }
    __syncthreads();

    // FMA: acc[8 b][4 g] over 32 k's (k = kq + 16*i)
    float acc[8][4] = {};
#pragma unroll
    for (int i = 0; i < 32; ++i) {
      const int k = kq + 16 * i;
      const float* hp = &h_lds[k * PADH + b0];
      float4 h0 = *(const float4*)hp;
      float4 h1 = *(const float4*)(hp + 4);
      float hv8[8] = {h0.x, h0.y, h0.z, h0.w, h1.x, h1.y, h1.z, h1.w};
#pragma unroll
      for (int bi = 0; bi < 8; ++bi)
#pragma unroll
        for (int g = 0; g < 4; ++g)
          acc[bi][g] += hv8[bi] * w_reg[i][g];
    }

    // wave-local reduce over 4 kq groups (lane bits 4,5)
#pragma unroll
    for (int bi = 0; bi < 8; ++bi)
#pragma unroll
      for (int g = 0; g < 4; ++g) {
        float v = acc[bi][g];
        v += __shfl_down(v, 32, 64);
        v += __shfl_down(v, 16, 64);
        acc[bi][g] = v;
      }
    if (lane < 16) {
#pragma unroll
      for (int e = 0; e < 32; ++e) red2[wv][lane][e] = acc[e >> 2][e & 3];
    }
    __syncthreads();

    // owners (tid<128): cross-wave combine + LSTM cell + LLC publish
    if (tid < 128) {
      float4 s0 = *(const float4*)&red2[0][rl][rbl * 4];
      float4 s1 = *(const float4*)&red2[1][rl][rbl * 4];
      float4 s2 = *(const float4*)&red2[2][rl][rbl * 4];
      float4 s3 = *(const float4*)&red2[3][rl][rbl * 4];
      const float gi = (s0.x + s1.x) + (s2.x + s3.x) + pre_s[buf][0][ob][ojj];
      const float gf = (s0.y + s1.y) + (s2.y + s3.y) + pre_s[buf][1][ob][ojj];
      const float gg = (s0.z + s1.z) + (s2.z + s3.z) + pre_s[buf][2][ob][ojj];
      const float go = (s0.w + s1.w) + (s2.w + s3.w) + pre_s[buf][3][ob][ojj];
      const float iv = sigf(gi);
      const float fv = sigf(gf);
      const float gv = tanhf(gg);
      const float ov = sigf(go);
      const float c = fv * c_reg + iv * gv;
      c_reg = c;
      const float h = ov * tanhf(c);
      float* hnxt = hT + (size_t)((t + 1) & 1) * (512 * NBAT);
      asm volatile("global_store_dword %0, %1, off sc0 sc1"
                   :: "v"(&hnxt[(j0 + ojj) * 32 + ob]), "v"(h) : "memory");
      Hout[((size_t)ob * 512 + t) * 512 + j0 + ojj] = h;
      asm volatile("s_waitcnt vmcnt(0)" ::: "memory");  // h at LLC before flag
      if ((tid & 63) == 0) {
        const int val = gen_base + t + 1;
        asm volatile("global_store_dword %0, %1, off sc0 sc1"
                     :: "v"(&flags[wg * 2 + wv]), "v"(val) : "memory");
      }
    }
  }
}

// ---------------------------------------------------------------------------
// Fused attention: out[b,q] = (1/8)*sum_h softmax_{d<=q}(QK^T/8)[d]*H2[b,q,d]*Wo[d] + bo
// ---------------------------------------------------------------------------
__device__ __forceinline__ int kswz(int row, int col) {
  return row * 64 + (col ^ (((row >> 2) & 7) << 2));
}

__global__ __launch_bounds__(256) void attn_kernel(
    const float* __restrict__ Qg, const float* __restrict__ Kg,
    const float* __restrict__ H2, const float* __restrict__ Wo,
    const float* __restrict__ bo, float* __restrict__ out) {
  __shared__ float Ks[64 * 64];
  __shared__ float part[4][16][68];
  __shared__ float s[16][512];
  __shared__ float Wo_s[512];

  const int tid = threadIdx.x;
  const int qt = blockIdx.x, b = blockIdx.y;
  const int q0 = qt * 16;
  const int dd = tid >> 6, qq = (tid >> 4) & 3, kq = tid & 15;
  const int srow = tid >> 4, slane = tid & 15;

  Wo_s[tid] = Wo[tid];
  Wo_s[256 + tid] = Wo[256 + tid];

  float out_reg = 0.f;
  const int kcmax = (q0 + 15) >> 6;

  for (int h = 0; h < 8; ++h) {
    float qreg[4][16];
#pragma unroll
    for (int r = 0; r < 4; ++r) {
      const float* qrow = Qg + ((size_t)(b * 512) + q0 + qq * 4 + r) * 512 + h * 64 + dd * 16;
#pragma unroll
      for (int i = 0; i < 16; i += 4) {
        float4 v = *(const float4*)(qrow + i);
        qreg[r][i] = v.x; qreg[r][i+1] = v.y; qreg[r][i+2] = v.z; qreg[r][i+3] = v.w;
      }
    }

    for (int kc = 0; kc <= kcmax; ++kc) {
      __syncthreads();
#pragma unroll
      for (int it = 0; it < 4; ++it) {
        const int f = tid * 4 + it * 1024;
        const int kk = f >> 6, d = f & 63;
        float4 v = *(const float4*)(Kg + ((size_t)(b * 512) + kc * 64 + kk) * 512 + h * 64 + d);
        Ks[kswz(d + 0, kk)] = v.x;
        Ks[kswz(d + 1, kk)] = v.y;
        Ks[kswz(d + 2, kk)] = v.z;
        Ks[kswz(d + 3, kk)] = v.w;
      }
      __syncthreads();

      float acc[4][4] = {};
#pragma unroll
      for (int i = 0; i < 16; ++i) {
        const int row = dd * 16 + i;
        float4 k4 = *(const float4*)&Ks[kswz(row, kq * 4)];
#pragma unroll
        for (int r = 0; r < 4; ++r) {
          acc[r][0] += qreg[r][i] * k4.x;
          acc[r][1] += qreg[r][i] * k4.y;
          acc[r][2] += qreg[r][i] * k4.z;
          acc[r][3] += qreg[r][i] * k4.w;
        }
      }
#pragma unroll
      for (int r = 0; r < 4; ++r)
        *(float4*)&part[dd][qq * 4 + r][kq * 4] =
            make_float4(acc[r][0], acc[r][1], acc[r][2], acc[r][3]);
      __syncthreads();
      {
        const int qi = tid >> 4, c = tid & 15;
        float4 p0 = *(const float4*)&part[0][qi][c * 4];
        float4 p1 = *(const float4*)&part[1][qi][c * 4];
        float4 p2 = *(const float4*)&part[2][qi][c * 4];
        float4 p3 = *(const float4*)&part[3][qi][c * 4];
        float4 r;
        r.x = ((p0.x + p1.x) + (p2.x + p3.x)) * 0.125f;
        r.y = ((p0.y + p1.y) + (p2.y + p3.y)) * 0.125f;
        r.z = ((p0.z + p1.z) + (p2.z + p3.z)) * 0.125f;
        r.w = ((p0.w + p1.w) + (p2.w + p3.w)) * 0.125f;
        *(float4*)&s[qi][kc * 64 + c * 4] = r;
      }
    }
    __syncthreads();

    const int q = q0 + srow;
    const int count = q + 1;
    const float* sp = &s[srow][0];
    float m = -1e30f;
    for (int d = slane; d < count; d += 16) m = fmaxf(m, sp[d]);
    m = fmaxf(m, __shfl_xor(m, 1, 64));
    m = fmaxf(m, __shfl_xor(m, 2, 64));
    m = fmaxf(m, __shfl_xor(m, 4, 64));
    m = fmaxf(m, __shfl_xor(m, 8, 64));
    float z = 0.f, zw = 0.f;
    const float* h2row = H2 + ((size_t)(b * 512) + q) * 512;
    for (int d = slane; d < count; d += 16) {
      const float e = __expf(sp[d] - m);
      z += e;
      zw += e * h2row[d] * Wo_s[d];
    }
    z += __shfl_xor(z, 1, 64); z += __shfl_xor(z, 2, 64);
    z += __shfl_xor(z, 4, 64); z += __shfl_xor(z, 8, 64);
    zw += __shfl_xor(zw, 1, 64); zw += __shfl_xor(zw, 2, 64);
    zw += __shfl_xor(zw, 4, 64); zw += __shfl_xor(zw, 8, 64);
    out_reg += zw / z;
    __syncthreads();
  }

  if (slane == 0)
    out[b * 512 + q0 + srow] = out_reg * 0.125f + bo[0];
}

// ---------------------------------------------------------------------------
extern "C" void kernel_launch(void* const* d_in, const int* in_sizes, int n_in,
                              void* d_out, int out_size, void* d_ws, size_t ws_size,
                              hipStream_t stream) {
  const float* x    = (const float*)d_in[0];
  const float* Wih0 = (const float*)d_in[1];
  const float* Whh0 = (const float*)d_in[2];
  const float* bih0 = (const float*)d_in[3];
  const float* bhh0 = (const float*)d_in[4];
  const float* Wih1 = (const float*)d_in[5];
  const float* Whh1 = (const float*)d_in[6];
  const float* bih1 = (const float*)d_in[7];
  const float* bhh1 = (const float*)d_in[8];
  const float* Wq   = (const float*)d_in[9];
  const float* bq   = (const float*)d_in[10];
  const float* Wk   = (const float*)d_in[11];
  const float* bk   = (const float*)d_in[12];
  const float* Wo   = (const float*)d_in[13];
  const float* bo   = (const float*)d_in[14];
  float* out = (float*)d_out;

  float* ws = (float*)d_ws;
  const size_t M = 16384;
  float* G  = ws;                                  // 16384*2048 floats
  float* H1 = G  + (size_t)16384 * 2048;           // 16384*512
  float* H2 = H1 + (size_t)16384 * 512;            // 16384*512
  float* hT = H2 + (size_t)16384 * 512;            // 2*16384 floats
  int* flags = (int*)(hT + 2 * 16384);             // 256 ints
  float* Qb = H1;   // reuse (H1 dead after layer-1 G gemm)
  float* Kb = G;    // reuse (G dead after layer-1 recurrence)

  // zero h state + flags every call (graph replay safe)
  hipMemsetAsync(hT, 0, (2 * 16384) * sizeof(float) + 256 * sizeof(int), stream);

  // layer 0
  gemm128<<<dim3(2048 / 128, M / 128), 256, 0, stream>>>(x, Wih0, bih0, bhh0, G,
                                                         (int)M, 2048, 256, 1);
  lstm_rec<<<128, 256, 0, stream>>>(G, Whh0, H1, hT, flags, 0);

  // layer 1 (re-zero hT only; flags continue monotonically via gen_base)
  hipMemsetAsync(hT, 0, (2 * 16384) * sizeof(float), stream);
  gemm128<<<dim3(2048 / 128, M / 128), 256, 0, stream>>>(H1, Wih1, bih1, bhh1, G,
                                                         (int)M, 2048, 512, 1);
  lstm_rec<<<128, 256, 0, stream>>>(G, Whh1, H2, hT, flags, 512);

  // Q/K projections
  gemm128<<<dim3(512 / 128, M / 128), 256, 0, stream>>>(H2, Wq, bq, nullptr, Qb,
                                                        (int)M, 512, 512, 0);
  gemm128<<<dim3(512 / 128, M / 128), 256, 0, stream>>>(H2, Wk, bk, nullptr, Kb,
                                                        (int)M, 512, 512, 0);

  // fused causal attention + head-mean + gated output
  attn_kernel<<<dim3(32, 32), 256, 0, stream>>>(Qb, Kb, H2, Wo, bo, out);
}